// Round 12
// baseline (369.421 us; speedup 1.0000x reference)
//
#include <hip/hip_runtime.h>

// conv3d(8ci->8co, 3x3x3, same) + relu/leaky/gelu/sigmoid + bias, via bf16 MFMA.
//
// GEMM view, DUAL-D: m = w-pos (16 per wave chunk), n = co + 8*s (s = d+s),
// k = tap'*8+ci, tap' over kd' in [0,4) x (kh,kw) = 36 taps = 9 K=32 steps.
// LDS [slice][h][w][ci] bf16, 6-slot ring, slice s -> slot (s+1)%6.
//
// History: R12 dual-d 114us | R13 spills 150 | R14 weak-barrier 146 |
// R15 w-split32 198 (write RMW; but occ 84% -> BW 3.15 TB/s!) |
// R16 +XCD swizzle 109.5us BEST: FETCH 155->73 MB (L3 retains x), WRITE 132
// ideal -- but dur -4% only => NOT traffic-bound anymore. Mfma 6.8/VALU 30/
// occ 37 (LDS-capped 4 blk/CU): ~63% stall = latency/TLP-bound.
//
// R17 (this): occupancy x2 with traffic-clean tiles. h-tile 4->1:
// SROWS 3, SLICEB 3168, ring 19 KB -> 8 blocks/CU by LDS. 4 waves split the
// 64-w tile into 4x16 chunks (1 MFMA tile, 9 MFMAs, 1 acc each). Writes stay
// 256B/segment per block-iter (R15's RMW trap avoided). h-halo: 3 rows staged
// per output row, but hb sits in the LOWEST logical bits under the XCD chunk
// swizzle (4096/8=512 blk/XCD, live x ~2-4 MB ~ L2) -> halo re-reads L2-local.
// __launch_bounds__(256,6) caps VGPR ~85 (bw[9]+aoff[9] ~45 persistent) --
// no spills (spill tell = symmetric FETCH+WRITE growth, R13 lesson).

#define CIN 8
#define COUT 8
#define DDIM 32
#define HDIM 128
#define WDIM 128
#define HWSZ (HDIM * WDIM)           // 16384
#define CISTR (DDIM * HWSZ)          // x ci stride in floats

#define ROWPTS 66                    // w = -1..64 (64-wide tile + halo)
#define ROWB   (ROWPTS * 16)         // 1056 B
#define SROWS  3                     // h = -1..1 (1-high tile + halo)
#define SLICEPTS (SROWS * ROWPTS)    // 198 points (<=256: 1 point/thread)
#define SLICEB (SROWS * ROWB)        // 3168 B
#define NSLOT 6
#define LDSB (NSLOT * SLICEB)        // 19008 B -> 8 blocks/CU by LDS
#define ND 16                        // output d per block (dsplit = 2); step 2

typedef short short8 __attribute__((ext_vector_type(8)));
typedef float floatx4 __attribute__((ext_vector_type(4)));

static __device__ __forceinline__ unsigned f2bf(float f) {
    unsigned u = __builtin_bit_cast(unsigned, f);
    return (u + 0x7FFFu + ((u >> 16) & 1u)) >> 16;   // RTN-even bf16
}

static __device__ __forceinline__ float act(float v, float bco) {
    float y = fmaxf(v, 0.f);                         // relu (leaky is identity after relu)
    float t = 0.7978845608028654f * (y + 0.044715f * y * y * y);
    float e = __builtin_amdgcn_exp2f(2.8853900817779268f * t);       // e^{2t}
    float g = y - y * __builtin_amdgcn_rcpf(1.f + e);                // tanh-gelu
    float s = __builtin_amdgcn_rcpf(1.f + __builtin_amdgcn_exp2f(-1.4426950408889634f * g));
    return s + bco;                                  // sigmoid + channel bias
}

// Block: 256 threads = 4 waves; wave wi handles w-chunk [W0+16*wi, +16) of the
// single output h-row. Grid: 128 hb * 2 wb * 8 b * 2 dsplit = 4096 blocks
// (hb in LOWEST logical bits); 8 dual-d iterations per block.
__global__ __launch_bounds__(256, 6) void conv3d_mfma_kernel(
    const float* __restrict__ x,
    const float* __restrict__ wgt,
    const float* __restrict__ bias,
    float* __restrict__ out)
{
    __shared__ __align__(16) char lds[LDSB];

    const int tid  = threadIdx.x;
    const int lane = tid & 63;
    const int wi   = tid >> 6;        // wave id = w-chunk 0..3
    const int m    = lane & 15;       // A-row (w pos in chunk); n = co+8*ds for B,C/D
    const int g    = lane >> 4;       // k-group 0..3
    const int co   = m & 7;           // output channel
    const int ds   = m >> 3;          // output d offset s in {0,1}

    // T1 XCD swizzle: XCD k gets logical blocks [k*512, (k+1)*512).
    const int bid = blockIdx.x;
    int bx = (bid & 7) * 512 + (bid >> 3);

    const int hb = bx & 127;  bx >>= 7;   // hb lowest: adjacent logical blocks
    const int wb = bx & 1;    bx >>= 1;   // share 2/3 staged h-rows (L2-local)
    const int b  = bx & 7;    bx >>= 3;
    const int d0 = bx * ND;           // d split: d0 in {0,16}
    const int h0 = hb;                // h-tile = 1 row
    const int W0 = wb * 64;
    const int dlim = d0 + ND;         // last slice index ever needed

    const float* xb = x + (size_t)b * CIN * CISTR;

    // ---- B fragments (weights), 9 k-steps over 36 taps', n = co+8*ds ----
    short8 bw[9];
    unsigned aoff[9];                 // per-lane A byte offset: kd'*SLICEB + spatial
    #pragma unroll
    for (int t = 0; t < 9; ++t) {
        const int tap = 4 * t + g;    // 0..35, no pad
        const int kd = tap / 9, r = tap % 9;
        const int kh = r / 3, kw = r % 3;
        const int kds = kd - ds;
        const bool wok = (kds >= 0) & (kds < 3);
        #pragma unroll
        for (int j = 0; j < 8; ++j) {
            float v = wok ? wgt[(co * CIN + j) * 27 + kds * 9 + kh * 3 + kw] : 0.f;
            bw[t][j] = (short)f2bf(v);
        }
        aoff[t] = (unsigned)(kd * SLICEB + kh * ROWB + (wi * 16 + m + kw) * 16);
    }
    const float bco = bias[co];

    // ---- staging geometry, d-invariant: 1 point per thread (p = tid < 198) ----
    const int p  = tid;
    const int hh = p / ROWPTS, ww = p - hh * ROWPTS;
    const int hg = h0 + hh - 1, wg = W0 + ww - 1;
    const bool okhw = (p < SLICEPTS) & ((unsigned)hg < HDIM) & ((unsigned)wg < WDIM);
    const int  soff = hg * WDIM + wg;       // junk when !okhw -- never dereferenced
    const int  ldso = p * 16;
    const bool wr0  = p < SLICEPTS;

    // ---- staging: slice dg -> slot (dg+1)%6, zero-fill outside the volume ----
    // Fused load+pack+write (R12 style): compiler overlaps it with MFMAs itself.
    auto stage = [&](int dg) {
        char* sb = lds + ((dg + 1) % NSLOT) * SLICEB;
        const float* xs = xb + (size_t)dg * HWSZ;
        const bool din = (unsigned)dg < DDIM;
        if (wr0) {
            const bool ok = okhw & din;
            const float* src = xs + soff;
            unsigned q[4];
            #pragma unroll
            for (int c = 0; c < 4; ++c) {
                float v0 = ok ? src[(2 * c    ) * CISTR] : 0.f;   // coalesced per-ci loads
                float v1 = ok ? src[(2 * c + 1) * CISTR] : 0.f;
                q[c] = f2bf(v0) | (f2bf(v1) << 16);
            }
            *(int4*)(sb + ldso) = make_int4(q[0], q[1], q[2], q[3]);
        }
    };

    // ---- prologue: slices d0-1 .. d0+2 ----
    stage(d0 - 1); stage(d0); stage(d0 + 1); stage(d0 + 2);
    __syncthreads();

    // slot of slice s is (s+1)%6; iter d reads slices d-1..d+2 -> slots (d..d+3)%6.
    unsigned sdB = (unsigned)(d0 % NSLOT) * SLICEB;

    for (int d = d0; d < dlim; d += 2) {
        // stage slices d+3,d+4 -> slots (d+4)%6,(d+5)%6; reads use (d..d+3)%6.
        if (d + 4 <= dlim) { stage(d + 3); stage(d + 4); }

        floatx4 acc0 = {0,0,0,0};
        #pragma unroll
        for (int t = 0; t < 9; ++t) {
            unsigned off = sdB + aoff[t];
            off = (off >= (unsigned)LDSB) ? off - (unsigned)LDSB : off;
            const char* ap = lds + off;
            short8 a0 = __builtin_bit_cast(short8, *(const int4*)(ap));
            acc0 = __builtin_amdgcn_mfma_f32_16x16x32_bf16(a0, bw[t], acc0, 0, 0, 0);
        }

        // C/D: col n = co+8*ds, rows g*4+reg = w within chunk -> one float4.
        // Block covers w 0..63 of this (co,d,h) row across waves: 256B segment.
        {
            float* op = out + ((size_t)(b * COUT + co) * DDIM + (d + ds)) * HWSZ
                            + h0 * WDIM + W0 + wi * 16 + g * 4;
            *(float4*)(op) = make_float4(act(acc0[0],bco), act(acc0[1],bco), act(acc0[2],bco), act(acc0[3],bco));
        }

        __syncthreads();
        sdB += 2 * SLICEB;
        if (sdB >= (unsigned)LDSB) sdB -= (unsigned)LDSB;
    }
}

extern "C" void kernel_launch(void* const* d_in, const int* in_sizes, int n_in,
                              void* d_out, int out_size, void* d_ws, size_t ws_size,
                              hipStream_t stream) {
    const float* x    = (const float*)d_in[0];
    const float* wgt  = (const float*)d_in[1];
    const float* bias = (const float*)d_in[2];
    float* out = (float*)d_out;

    dim3 grid(128 * 2 * 8 * 2);   // hb * wb * b * dsplit = 4096 logical blocks
    dim3 block(256);
    conv3d_mfma_kernel<<<grid, block, 0, stream>>>(x, wgt, bias, out);
}

// Round 13
// 313.512 us; speedup vs baseline: 1.1783x; 1.1783x over previous
//
#include <hip/hip_runtime.h>

// conv3d(8ci->8co, 3x3x3, same) + relu/leaky/gelu/sigmoid + bias, via bf16 MFMA.
//
// GEMM view (single-d per wave): D[m][n]: m = w-pos (16/chunk), n = co (8 of
// 16), k = tap*8+ci, tap = kd*9+kh*3+kw in [0,27), padded to 28 (7 K=32 steps).
// Wave role = (hr, dw): one full (h,d) output row of 64 w x 8 co per wave.
// LDS [slice][h(4)][w(66)][ci(8)] bf16, 6-slot ring, slice s -> slot (s+1)%6.
//
// History: R12 dual-d 114 | R15 w32 198 (128B sectors cross-XCD -> RMW) |
// R16 +XCD swizzle 109.5 BEST (FETCH 73, WRITE 132 ideal, occ 37, no pipe
// >31% -> TLP-bound) | R17 h1 215 (64B per-wave write fragments -> RMW,
// WRITE 280; h-halo 3x -> FETCH 172; occ 61 proves the lever).
// TRAFFIC LAWS (measured): (1) each 256B output sector written by ONE wave,
// contiguously (R16 clean / R15 / R17 dirty); (2) block-adjacent halo reuse
// must be XCD-local (R16 FETCH 155->73); (3) schedule surgery always lost
// (R11/R13/R14); tile/traffic changes won (dual-d, swizzle).
//
// R18 (this): h-tile 2, wave=(hr,dw). 4 waves x [64w x 8co] rows, per-(co)
// stores = 4 consecutive dwordx4 = 256B/wave (law 1). Slice 4224B, ring
// 25.3KB -> 6 blocks/CU = 24 waves (75%); grid 2048 = hb64(low) x wb2 x b8
// x dsplit2, XCD chunks 256 -> hb-halo L2-local (law 2). Iteration skeleton
// EXACTLY R16: fused stage, one __syncthreads, no pins (law 3).
// Pad tap 27 -> kdo=0 (always-staged slot; B=0; NaN-safe per R4 fix).

#define CIN 8
#define COUT 8
#define DDIM 32
#define HDIM 128
#define WDIM 128
#define HWSZ (HDIM * WDIM)           // 16384
#define CISTR (DDIM * HWSZ)          // x ci stride in floats

#define ROWPTS 66                    // w = -1..64 (64-wide tile + halo)
#define ROWB   (ROWPTS * 16)         // 1056 B
#define SROWS  4                     // h = -1..2 (2-high tile + halo)
#define SLICEPTS (SROWS * ROWPTS)    // 264 points
#define SLICEB (SROWS * ROWB)        // 4224 B
#define NSLOT 6
#define LDSB (NSLOT * SLICEB)        // 25344 B -> 6 blocks/CU = 24 waves (75%)
#define ND 16                        // output d per block (dsplit = 2); step 2

typedef short short8 __attribute__((ext_vector_type(8)));
typedef float floatx4 __attribute__((ext_vector_type(4)));

static __device__ __forceinline__ unsigned f2bf(float f) {
    unsigned u = __builtin_bit_cast(unsigned, f);
    return (u + 0x7FFFu + ((u >> 16) & 1u)) >> 16;   // RTN-even bf16
}

static __device__ __forceinline__ float act(float v, float bco) {
    float y = fmaxf(v, 0.f);                         // relu (leaky is identity after relu)
    float t = 0.7978845608028654f * (y + 0.044715f * y * y * y);
    float e = __builtin_amdgcn_exp2f(2.8853900817779268f * t);       // e^{2t}
    float g = y - y * __builtin_amdgcn_rcpf(1.f + e);                // tanh-gelu
    float s = __builtin_amdgcn_rcpf(1.f + __builtin_amdgcn_exp2f(-1.4426950408889634f * g));
    return s + bco;                                  // sigmoid + channel bias
}

// Block: 256 threads = 4 waves; wave (hr,dw) -> output row (h0+hr, d+dw), 64 w.
// Grid: 64 hb (LOW bits) * 2 wb * 8 b * 2 dsplit = 2048; 8 iterations per block.
__global__ __launch_bounds__(256, 6) void conv3d_mfma_kernel(
    const float* __restrict__ x,
    const float* __restrict__ wgt,
    const float* __restrict__ bias,
    float* __restrict__ out)
{
    __shared__ __align__(16) char lds[LDSB];

    const int tid  = threadIdx.x;
    const int lane = tid & 63;
    const int wid  = tid >> 6;
    const int hr   = wid & 1;         // wave's h row within tile
    const int dw   = wid >> 1;        // wave's d offset within pair
    const int m    = lane & 15;       // A-row (w pos); n = co for B,C/D (m<8)
    const int g    = lane >> 4;       // k-group 0..3

    // T1 XCD swizzle: XCD k gets logical blocks [k*256, (k+1)*256).
    const int bid = blockIdx.x;
    int bx = (bid & 7) * 256 + (bid >> 3);

    const int hb = bx & 63;  bx >>= 6;    // hb lowest: halo-sharing neighbors
    const int wb = bx & 1;   bx >>= 1;    // stay on the same XCD, same time
    const int b  = bx & 7;   bx >>= 3;
    const int d0 = bx * ND;           // d split: d0 in {0,16}
    const int h0 = hb * 2;
    const int W0 = wb * 64;
    const int dlim = d0 + ND;         // last slice index ever needed

    const float* xb = x + (size_t)b * CIN * CISTR;

    // ---- B fragments (weights), 7 k-steps, n = m (co, m<8), tap = 4t+g ----
    short8 bw[7];
    unsigned aoff[7];                 // per-lane A byte offset within ring
    #pragma unroll
    for (int t = 0; t < 7; ++t) {
        const int tap = 4 * t + g;    // 0..27 (27 = zero pad)
        const int kd = tap / 9, r = tap % 9;
        const int kh = r / 3, kw = r % 3;
        const int kdo = (tap < 27) ? kd : 0;   // pad tap -> always-staged slot
        #pragma unroll
        for (int j = 0; j < 8; ++j) {
            float v = (m < 8 && tap < 27) ? wgt[(m * CIN + j) * 27 + tap] : 0.f;
            bw[t][j] = (short)f2bf(v);
        }
        // slice read = (d+dw) + kd - 1 -> slot (d + dw + kd)%6
        aoff[t] = (unsigned)((dw + kdo) * SLICEB + (hr + kh) * ROWB + (m + kw) * 16);
    }
    const float bco = (m < 8) ? bias[m] : 0.f;

    // ---- staging geometry, d-invariant: points p = tid, tid+256 (264 total) ----
    int  soff[2];
    bool okhw[2];
    int  ldso[2];
    #pragma unroll
    for (int i = 0; i < 2; ++i) {
        const int p  = tid + 256 * i;
        const int hh = p / ROWPTS, ww = p - hh * ROWPTS;
        const int hg = h0 + hh - 1, wg = W0 + ww - 1;
        okhw[i] = (p < SLICEPTS) & ((unsigned)hg < HDIM) & ((unsigned)wg < WDIM);
        soff[i] = hg * WDIM + wg;          // junk when !okhw -- never dereferenced
        ldso[i] = p * 16;
    }

    // ---- staging: slice dg -> slot (dg+1)%6, zero-fill outside the volume ----
    // Fused load+pack+write (R16 style): compiler overlaps it with MFMAs itself.
    auto stage = [&](int dg) {
        char* sb = lds + ((dg + 1) % NSLOT) * SLICEB;
        const float* xs = xb + (size_t)dg * HWSZ;
        const bool din = (unsigned)dg < DDIM;
        #pragma unroll
        for (int i = 0; i < 2; ++i) {
            const int p = tid + 256 * i;
            if (p < SLICEPTS) {
                const bool ok = okhw[i] & din;
                const float* src = xs + soff[i];
                unsigned q[4];
                #pragma unroll
                for (int c = 0; c < 4; ++c) {
                    float v0 = ok ? src[(2 * c    ) * CISTR] : 0.f;   // coalesced per-ci loads
                    float v1 = ok ? src[(2 * c + 1) * CISTR] : 0.f;
                    q[c] = f2bf(v0) | (f2bf(v1) << 16);
                }
                *(int4*)(sb + ldso[i]) = make_int4(q[0], q[1], q[2], q[3]);
            }
        }
    };

    // ---- prologue: slices d0-1 .. d0+2 ----
    stage(d0 - 1); stage(d0); stage(d0 + 1); stage(d0 + 2);
    __syncthreads();

    // iter d reads slices d-1..d+2 -> slots (d..d+3)%6; stages d+3,d+4 ->
    // slots (d+4)%6,(d+5)%6 -- disjoint.
    unsigned sdB = (unsigned)(d0 % NSLOT) * SLICEB;

    for (int d = d0; d < dlim; d += 2) {
        if (d + 4 <= dlim) { stage(d + 3); stage(d + 4); }

        floatx4 acc0 = {0,0,0,0}, acc1 = {0,0,0,0}, acc2 = {0,0,0,0}, acc3 = {0,0,0,0};
        #pragma unroll
        for (int t = 0; t < 7; ++t) {
            unsigned off = sdB + aoff[t];
            off = (off >= (unsigned)LDSB) ? off - (unsigned)LDSB : off;
            const char* ap = lds + off;
            short8 a0 = __builtin_bit_cast(short8, *(const int4*)(ap      ));
            short8 a1 = __builtin_bit_cast(short8, *(const int4*)(ap + 256));
            short8 a2 = __builtin_bit_cast(short8, *(const int4*)(ap + 512));
            short8 a3 = __builtin_bit_cast(short8, *(const int4*)(ap + 768));
            acc0 = __builtin_amdgcn_mfma_f32_16x16x32_bf16(a0, bw[t], acc0, 0, 0, 0);
            acc1 = __builtin_amdgcn_mfma_f32_16x16x32_bf16(a1, bw[t], acc1, 0, 0, 0);
            acc2 = __builtin_amdgcn_mfma_f32_16x16x32_bf16(a2, bw[t], acc2, 0, 0, 0);
            acc3 = __builtin_amdgcn_mfma_f32_16x16x32_bf16(a3, bw[t], acc3, 0, 0, 0);
        }

        // C/D: col n = m (co), rows g*4+reg -> 4 consecutive w. Per (co): this
        // wave writes 4 consecutive dwordx4 = 256B contiguous (traffic law 1).
        if (m < 8) {
            float* op = out + ((size_t)(b * COUT + m) * DDIM + (d + dw)) * HWSZ
                            + (h0 + hr) * WDIM + W0 + g * 4;
            *(float4*)(op)      = make_float4(act(acc0[0],bco), act(acc0[1],bco), act(acc0[2],bco), act(acc0[3],bco));
            *(float4*)(op + 16) = make_float4(act(acc1[0],bco), act(acc1[1],bco), act(acc1[2],bco), act(acc1[3],bco));
            *(float4*)(op + 32) = make_float4(act(acc2[0],bco), act(acc2[1],bco), act(acc2[2],bco), act(acc2[3],bco));
            *(float4*)(op + 48) = make_float4(act(acc3[0],bco), act(acc3[1],bco), act(acc3[2],bco), act(acc3[3],bco));
        }

        __syncthreads();
        sdB += 2 * SLICEB;
        if (sdB >= (unsigned)LDSB) sdB -= (unsigned)LDSB;
    }
}

extern "C" void kernel_launch(void* const* d_in, const int* in_sizes, int n_in,
                              void* d_out, int out_size, void* d_ws, size_t ws_size,
                              hipStream_t stream) {
    const float* x    = (const float*)d_in[0];
    const float* wgt  = (const float*)d_in[1];
    const float* bias = (const float*)d_in[2];
    float* out = (float*)d_out;

    dim3 grid(64 * 2 * 8 * 2);   // hb * wb * b * dsplit = 2048 logical blocks
    dim3 block(256);
    conv3d_mfma_kernel<<<grid, block, 0, stream>>>(x, wgt, bias, out);
}

// Round 14
// 261.358 us; speedup vs baseline: 1.4135x; 1.1995x over previous
//
#include <hip/hip_runtime.h>

// conv3d(8ci->8co, 3x3x3, same) + relu/leaky/gelu/sigmoid + bias, via bf16 MFMA.
//
// GEMM view, DUAL-D (R12/R16): m = w-pos (16/chunk), n = co + 8*s (s = d+s),
// k = tap'*8+ci, tap' over kd' in [0,4) x (kh,kw) = 36 taps = 9 K=32 steps.
// LDS [slice][h][w][ci] bf16, 6-slot ring, slice s -> slot (s+1)%6.
//
// History: R12 dual-d 114 | R16 +XCD swizzle 109.5 BEST (FETCH 73, WRITE 132
// ideal, occ 37, no pipe >31%) | R15/R17/R18 all broke traffic.
// MEASURED LAWS: (1) each 256B output sector written by ONE wave contiguously;
// (2) XCD chunk must EQUAL per-XCD concurrent capacity (R16: 128=128 clean;
// R18: 256>192 broke) and live x window <= 4MB L2; (3) schedule surgery
// always lost (R11/R13/R14); (4) h-halo redundancy = SROWS/h-tile scales
// demand reads (R18: 2.0x -> FETCH 122; R16: 1.5x -> 73).
//
// R19 (this): h-tile 8, 512 threads = 8 waves (wave wid = h-row, dual-d in n).
// Halo redundancy 1.5 -> 1.25 (demand reads 233->195 MB). All R16 invariants
// kept: same per-wave 256B stores, same fused stage + one __syncthreads,
// LDS 63.4KB -> 2 blocks/CU x 8 waves = 16 waves/CU (= R16), grid 512 = zero
// tail, XCD chunk 64 = exact capacity, live window ~4.2MB ~ L2.
// Risk: 2 barrier groups/CU (vs 4) -- coarser cross-block overlap.

#define CIN 8
#define COUT 8
#define DDIM 32
#define HDIM 128
#define WDIM 128
#define HWSZ (HDIM * WDIM)           // 16384
#define CISTR (DDIM * HWSZ)          // x ci stride in floats

#define ROWPTS 66                    // w = -1..64 (64-wide tile + halo)
#define ROWB   (ROWPTS * 16)         // 1056 B
#define SROWS  10                    // h = -1..8 (8-high tile + halo)
#define SLICEPTS (SROWS * ROWPTS)    // 660 points
#define SLICEB (SROWS * ROWB)        // 10560 B
#define NSLOT 6
#define LDSB (NSLOT * SLICEB)        // 63360 B -> 2 blocks/CU (126.7 of 160 KB)
#define ND 16                        // output d per block (dsplit = 2); step 2

typedef short short8 __attribute__((ext_vector_type(8)));
typedef float floatx4 __attribute__((ext_vector_type(4)));

static __device__ __forceinline__ unsigned f2bf(float f) {
    unsigned u = __builtin_bit_cast(unsigned, f);
    return (u + 0x7FFFu + ((u >> 16) & 1u)) >> 16;   // RTN-even bf16
}

static __device__ __forceinline__ float act(float v, float bco) {
    float y = fmaxf(v, 0.f);                         // relu (leaky is identity after relu)
    float t = 0.7978845608028654f * (y + 0.044715f * y * y * y);
    float e = __builtin_amdgcn_exp2f(2.8853900817779268f * t);       // e^{2t}
    float g = y - y * __builtin_amdgcn_rcpf(1.f + e);                // tanh-gelu
    float s = __builtin_amdgcn_rcpf(1.f + __builtin_amdgcn_exp2f(-1.4426950408889634f * g));
    return s + bco;                                  // sigmoid + channel bias
}

// Block: 512 threads = 8 waves; wave wid = output h-row (h0+wid), 4 w-chunks.
// Grid: 16 hb (LOW bits) * 2 wb * 8 b * 2 dsplit = 512; 8 dual-d iters/block.
__global__ __launch_bounds__(512, 4) void conv3d_mfma_kernel(
    const float* __restrict__ x,
    const float* __restrict__ wgt,
    const float* __restrict__ bias,
    float* __restrict__ out)
{
    __shared__ __align__(16) char lds[LDSB];

    const int tid  = threadIdx.x;
    const int lane = tid & 63;
    const int wid  = tid >> 6;        // wave id = local h row 0..7
    const int m    = lane & 15;       // A-row (w pos); n = co + 8*ds for B, C/D
    const int g    = lane >> 4;       // k-group 0..3
    const int co   = m & 7;           // output channel
    const int ds   = m >> 3;          // output d offset s in {0,1}

    // T1 XCD swizzle: XCD k gets logical blocks [k*64, (k+1)*64) -- chunk 64
    // = exact per-XCD concurrent capacity (32 CU x 2 blocks).
    const int bid = blockIdx.x;
    int bx = (bid & 7) * 64 + (bid >> 3);

    const int hb = bx & 15;  bx >>= 4;    // hb lowest: halo-sharing neighbors
    const int wb = bx & 1;   bx >>= 1;    // co-resident on the same XCD
    const int b  = bx & 7;   bx >>= 3;
    const int d0 = bx * ND;           // d split: d0 in {0,16}
    const int h0 = hb * 8;
    const int W0 = wb * 64;
    const int dlim = d0 + ND;         // last slice index ever needed

    const float* xb = x + (size_t)b * CIN * CISTR;

    // ---- B fragments (weights), 9 k-steps over 36 taps', n = co+8*ds ----
    short8 bw[9];
    unsigned aoff[9];                 // per-lane A byte offset: kd'*SLICEB + spatial
    #pragma unroll
    for (int t = 0; t < 9; ++t) {
        const int tap = 4 * t + g;    // 0..35, no pad
        const int kd = tap / 9, r = tap % 9;
        const int kh = r / 3, kw = r % 3;
        const int kds = kd - ds;
        const bool wok = (kds >= 0) & (kds < 3);
        #pragma unroll
        for (int j = 0; j < 8; ++j) {
            float v = wok ? wgt[(co * CIN + j) * 27 + kds * 9 + kh * 3 + kw] : 0.f;
            bw[t][j] = (short)f2bf(v);
        }
        aoff[t] = (unsigned)(kd * SLICEB + (wid + kh) * ROWB + (m + kw) * 16);
    }
    const float bco = bias[co];

    // ---- staging geometry, d-invariant: points p = tid, tid+512 (660 total) ----
    int  soff[2];
    bool okhw[2];
    int  ldso[2];
    #pragma unroll
    for (int i = 0; i < 2; ++i) {
        const int p  = tid + 512 * i;
        const int hh = p / ROWPTS, ww = p - hh * ROWPTS;
        const int hg = h0 + hh - 1, wg = W0 + ww - 1;
        okhw[i] = (p < SLICEPTS) & ((unsigned)hg < HDIM) & ((unsigned)wg < WDIM);
        soff[i] = hg * WDIM + wg;          // junk when !okhw -- never dereferenced
        ldso[i] = p * 16;
    }

    // ---- staging: slice dg -> slot (dg+1)%6, zero-fill outside the volume ----
    // Fused load+pack+write (R16 style): compiler overlaps it with MFMAs itself.
    auto stage = [&](int dg) {
        char* sb = lds + ((dg + 1) % NSLOT) * SLICEB;
        const float* xs = xb + (size_t)dg * HWSZ;
        const bool din = (unsigned)dg < DDIM;
        #pragma unroll
        for (int i = 0; i < 2; ++i) {
            const int p = tid + 512 * i;
            if (p < SLICEPTS) {
                const bool ok = okhw[i] & din;
                const float* src = xs + soff[i];
                unsigned q[4];
                #pragma unroll
                for (int c = 0; c < 4; ++c) {
                    float v0 = ok ? src[(2 * c    ) * CISTR] : 0.f;   // coalesced per-ci loads
                    float v1 = ok ? src[(2 * c + 1) * CISTR] : 0.f;
                    q[c] = f2bf(v0) | (f2bf(v1) << 16);
                }
                *(int4*)(sb + ldso[i]) = make_int4(q[0], q[1], q[2], q[3]);
            }
        }
    };

    // ---- prologue: slices d0-1 .. d0+2 ----
    stage(d0 - 1); stage(d0); stage(d0 + 1); stage(d0 + 2);
    __syncthreads();

    // iter d reads slices d-1..d+2 -> slots (d..d+3)%6; stages d+3,d+4 ->
    // slots (d+4)%6,(d+5)%6 -- disjoint.
    unsigned sdB = (unsigned)(d0 % NSLOT) * SLICEB;

    for (int d = d0; d < dlim; d += 2) {
        if (d + 4 <= dlim) { stage(d + 3); stage(d + 4); }

        floatx4 acc0 = {0,0,0,0}, acc1 = {0,0,0,0}, acc2 = {0,0,0,0}, acc3 = {0,0,0,0};
        #pragma unroll
        for (int t = 0; t < 9; ++t) {
            unsigned off = sdB + aoff[t];
            off = (off >= (unsigned)LDSB) ? off - (unsigned)LDSB : off;
            const char* ap = lds + off;
            short8 a0 = __builtin_bit_cast(short8, *(const int4*)(ap      ));
            short8 a1 = __builtin_bit_cast(short8, *(const int4*)(ap + 256));
            short8 a2 = __builtin_bit_cast(short8, *(const int4*)(ap + 512));
            short8 a3 = __builtin_bit_cast(short8, *(const int4*)(ap + 768));
            acc0 = __builtin_amdgcn_mfma_f32_16x16x32_bf16(a0, bw[t], acc0, 0, 0, 0);
            acc1 = __builtin_amdgcn_mfma_f32_16x16x32_bf16(a1, bw[t], acc1, 0, 0, 0);
            acc2 = __builtin_amdgcn_mfma_f32_16x16x32_bf16(a2, bw[t], acc2, 0, 0, 0);
            acc3 = __builtin_amdgcn_mfma_f32_16x16x32_bf16(a3, bw[t], acc3, 0, 0, 0);
        }

        // C/D: col n = co+8*ds, rows = g*4+reg -> 4 consecutive w. Per (co,ds):
        // this wave writes 4 consecutive dwordx4 = 256B contiguous (law 1).
        {
            float* op = out + ((size_t)(b * COUT + co) * DDIM + (d + ds)) * HWSZ
                            + (h0 + wid) * WDIM + W0 + g * 4;
            *(float4*)(op)      = make_float4(act(acc0[0],bco), act(acc0[1],bco), act(acc0[2],bco), act(acc0[3],bco));
            *(float4*)(op + 16) = make_float4(act(acc1[0],bco), act(acc1[1],bco), act(acc1[2],bco), act(acc1[3],bco));
            *(float4*)(op + 32) = make_float4(act(acc2[0],bco), act(acc2[1],bco), act(acc2[2],bco), act(acc2[3],bco));
            *(float4*)(op + 48) = make_float4(act(acc3[0],bco), act(acc3[1],bco), act(acc3[2],bco), act(acc3[3],bco));
        }

        __syncthreads();
        sdB += 2 * SLICEB;
        if (sdB >= (unsigned)LDSB) sdB -= (unsigned)LDSB;
    }
}

extern "C" void kernel_launch(void* const* d_in, const int* in_sizes, int n_in,
                              void* d_out, int out_size, void* d_ws, size_t ws_size,
                              hipStream_t stream) {
    const float* x    = (const float*)d_in[0];
    const float* wgt  = (const float*)d_in[1];
    const float* bias = (const float*)d_in[2];
    float* out = (float*)d_out;

    dim3 grid(16 * 2 * 8 * 2);   // hb * wb * b * dsplit = 512 logical blocks
    dim3 block(512);
    conv3d_mfma_kernel<<<grid, block, 0, stream>>>(x, wgt, bias, out);
}